// Round 1
// baseline (14.050 us; speedup 1.0000x reference)
//
#include <hip/hip_runtime.h>
#include <math.h>

#define UNITS 128

// out_b = x_b @ expm(t_b * K)  ==  expm(t_b * K^T) @ x_b
// K tridiagonal: K[i][i]=sigma[i], K[i][i+1]=ceta[i], K[i+1][i]=-ceta[i]
// A = t*K^T:  (A w)[i] = t*( sigma[i]*w[i] - ceta[i]*w[i+1] + ceta[i-1]*w[i-1] )
//
// One wave (64 lanes) per batch element; lane l owns rows 2l and 2l+1.
// expm(A) x via scaling (s = ceil(||A||_inf)) + degree-10 Taylor per sub-step.
// Symmetric part of A is t*diag(sigma) <= 0  =>  contraction => stable.

__global__ __launch_bounds__(256) void expv_kernel(
    const float* __restrict__ inputs,   // [B, UNITS+1]
    const float* __restrict__ params,   // [2*UNITS-1]
    float* __restrict__ out,            // [B, UNITS]
    int B)
{
    const int gid  = blockIdx.x * blockDim.x + threadIdx.x;
    const int wave = gid >> 6;
    const int lane = gid & 63;
    if (wave >= B) return;

    const int i0 = lane * 2;

    // ---- batch-independent coefficients (recomputed per wave; 2 exps/lane) ----
    const float p0 = params[i0];
    const float p1 = params[i0 + 1];
    // stable softplus
    const float sp0 = fmaxf(p0, 0.f) + log1pf(expf(-fabsf(p0)));
    const float sp1 = fmaxf(p1, 0.f) + log1pf(expf(-fabsf(p1)));
    const float sig0 = -sp0 * sp0;          // sigma[2l]
    const float sig1 = -sp1 * sp1;          // sigma[2l+1]
    // ceta[j] = -params[UNITS + j], valid j = 0..UNITS-2 (=126)
    const float ce0 = -params[UNITS + i0];                        // ceta[2l]   (2l <= 126 always)
    const float ce1 = (lane < 63) ? -params[UNITS + i0 + 1] : 0.f; // ceta[2l+1] (0 at boundary)
    const float ced = (lane > 0)  ? -params[UNITS + i0 - 1] : 0.f; // ceta[2l-1] (0 at boundary)

    // ---- per-element data ----
    const float* row = inputs + (size_t)wave * (UNITS + 1);
    const float x0 = row[i0];
    const float x1 = row[i0 + 1];
    const float t  = row[UNITS];

    // scaled tridiagonal coefficients of A = t*K^T
    const float a0 = t * sig0;
    const float a1 = t * sig1;
    const float c0 = t * ce0;
    const float c1 = t * ce1;
    const float cd = t * ced;

    // ||A||_inf : max row abs-sum, wave-reduced
    float r = fmaxf(fabsf(a0) + fabsf(c0) + fabsf(cd),
                    fabsf(a1) + fabsf(c1) + fabsf(c0));
    #pragma unroll
    for (int off = 32; off >= 1; off >>= 1)
        r = fmaxf(r, __shfl_xor(r, off, 64));

    int s = (int)ceilf(r);
    s = (s < 1) ? 1 : ((s > 64) ? 64 : s);
    const float inv_s = 1.0f / (float)s;

    // w = (Taylor_10(A/s))^s x
    float w0 = x0, w1 = x1;
    for (int step = 0; step < s; ++step) {
        float q0 = w0, q1 = w1;        // current Taylor term
        float acc0 = w0, acc1 = w1;    // partial sum
        #pragma unroll
        for (int k = 1; k <= 10; ++k) {
            const float qdn = __shfl_up(q1, 1, 64);    // w[2l-1] (garbage at lane 0, cd=0)
            const float qup = __shfl_down(q0, 1, 64);  // w[2l+2] (garbage at lane 63, c1=0)
            const float f = inv_s * (1.0f / (float)k); // 1/k folds to constant under unroll
            const float n0 = (a0 * q0 - c0 * q1 + cd * qdn) * f;
            const float n1 = (a1 * q1 - c1 * qup + c0 * q0) * f;
            q0 = n0; q1 = n1;
            acc0 += q0; acc1 += q1;
        }
        w0 = acc0; w1 = acc1;
    }

    // coalesced float2 store (row offset = wave*512 B, 8-aligned)
    float2* orow = (float2*)(out + (size_t)wave * UNITS);
    orow[lane] = make_float2(w0, w1);
}

extern "C" void kernel_launch(void* const* d_in, const int* in_sizes, int n_in,
                              void* d_out, int out_size, void* d_ws, size_t ws_size,
                              hipStream_t stream) {
    const float* inputs = (const float*)d_in[0];
    const float* params = (const float*)d_in[1];
    float* out = (float*)d_out;

    const int B = in_sizes[0] / (UNITS + 1);   // 4096
    const int waves_per_block = 4;             // 256 threads
    const int block = 64 * waves_per_block;
    const int grid  = (B + waves_per_block - 1) / waves_per_block;

    expv_kernel<<<grid, block, 0, stream>>>(inputs, params, out, B);
}

// Round 2
// 11.434 us; speedup vs baseline: 1.2287x; 1.2287x over previous
//
#include <hip/hip_runtime.h>
#include <math.h>

#define UNITS 128
#define THETA 4.0f
#define MDEG  16

// out_b = x_b @ expm(t_b * K)  ==  expm(t_b * K^T) @ x_b
// K tridiagonal: K[i][i]=sigma[i], K[i][i+1]=ceta[i], K[i+1][i]=-ceta[i]
// A = t*K^T:  (A w)[i] = t*( sigma[i]*w[i] - ceta[i]*w[i+1] + ceta[i-1]*w[i-1] )
//
// One wave handles TWO batch elements (ILP-2 to hide shuffle latency);
// lane l owns rows 2l, 2l+1 of both. expm via scaling (s = ceil(r/THETA))
// + degree-MDEG Taylor per sub-step. Symmetric part of A = t*diag(sigma) <= 0
// => contraction => unconditionally stable.

__global__ __launch_bounds__(256) void expv_kernel(
    const float* __restrict__ inputs,   // [B, UNITS+1]
    const float* __restrict__ params,   // [2*UNITS-1]
    float* __restrict__ out,            // [B, UNITS]
    int B)
{
    const int gid  = blockIdx.x * blockDim.x + threadIdx.x;
    const int wave = gid >> 6;
    const int lane = gid & 63;
    const int eA   = wave * 2;
    if (eA >= B) return;
    const int  eB   = eA + 1;
    const bool hasB = (eB < B);

    const int i0 = lane * 2;

    // ---- batch-independent K coefficients ----
    const float p0 = params[i0];
    const float p1 = params[i0 + 1];
    const float sp0 = fmaxf(p0, 0.f) + log1pf(expf(-fabsf(p0)));  // stable softplus
    const float sp1 = fmaxf(p1, 0.f) + log1pf(expf(-fabsf(p1)));
    const float sig0 = -sp0 * sp0;                                 // sigma[2l]
    const float sig1 = -sp1 * sp1;                                 // sigma[2l+1]
    const float ce0 = -params[UNITS + i0];                         // ceta[2l]
    const float ce1 = (lane < 63) ? -params[UNITS + i0 + 1] : 0.f; // ceta[2l+1]
    const float ced = (lane > 0)  ? -params[UNITS + i0 - 1] : 0.f; // ceta[2l-1]

    // ||K||_inf (batch-independent): max row abs-sum, wave-reduced
    float rm = fmaxf(fabsf(sig0) + fabsf(ce0) + fabsf(ced),
                     fabsf(sig1) + fabsf(ce1) + fabsf(ce0));
    #pragma unroll
    for (int off = 32; off >= 1; off >>= 1)
        rm = fmaxf(rm, __shfl_xor(rm, off, 64));

    // ---- per-element data ----
    const float* rowA = inputs + (size_t)eA * (UNITS + 1);
    const float* rowB = inputs + (size_t)(hasB ? eB : eA) * (UNITS + 1);
    const float x0A = rowA[i0], x1A = rowA[i0 + 1], tA = rowA[UNITS];
    const float x0B = rowB[i0], x1B = rowB[i0 + 1], tB = rowB[UNITS];

    // shared sub-step count from the larger of the two ||A||_inf
    const float r = rm * fmaxf(tA, tB);
    int s = (int)ceilf(r / THETA);
    s = (s < 1) ? 1 : ((s > 64) ? 64 : s);
    const float inv_s = 1.0f / (float)s;

    // pre-scaled tridiagonal coefficients of A/s per element
    const float fA = tA * inv_s, fB = tB * inv_s;
    const float a0A = sig0 * fA, a1A = sig1 * fA;
    const float c0A = ce0 * fA,  c1A = ce1 * fA,  cdA = ced * fA;
    const float a0B = sig0 * fB, a1B = sig1 * fB;
    const float c0B = ce0 * fB,  c1B = ce1 * fB,  cdB = ced * fB;

    // w = (Taylor_MDEG(A/s))^s x, two independent chains interleaved
    float w0A = x0A, w1A = x1A;
    float w0B = x0B, w1B = x1B;
    for (int step = 0; step < s; ++step) {
        float q0A = w0A, q1A = w1A, acc0A = w0A, acc1A = w1A;
        float q0B = w0B, q1B = w1B, acc0B = w0B, acc1B = w1B;
        #pragma unroll
        for (int k = 1; k <= MDEG; ++k) {
            const float dA = __shfl_up  (q1A, 1, 64);  // w[2l-1] (lane0 garbage, cd=0)
            const float uA = __shfl_down(q0A, 1, 64);  // w[2l+2] (lane63 garbage, c1=0)
            const float dB = __shfl_up  (q1B, 1, 64);
            const float uB = __shfl_down(q0B, 1, 64);
            const float ck = 1.0f / (float)k;          // compile-time constant
            const float n0A = (a0A * q0A - c0A * q1A + cdA * dA) * ck;
            const float n1A = (a1A * q1A - c1A * uA  + c0A * q0A) * ck;
            const float n0B = (a0B * q0B - c0B * q1B + cdB * dB) * ck;
            const float n1B = (a1B * q1B - c1B * uB  + c0B * q0B) * ck;
            q0A = n0A; q1A = n1A; acc0A += q0A; acc1A += q1A;
            q0B = n0B; q1B = n1B; acc0B += q0B; acc1B += q1B;
        }
        w0A = acc0A; w1A = acc1A;
        w0B = acc0B; w1B = acc1B;
    }

    // coalesced float2 stores (row offset = e*512 B, 8-aligned)
    float2* orA = (float2*)(out + (size_t)eA * UNITS);
    orA[lane] = make_float2(w0A, w1A);
    if (hasB) {
        float2* orB = (float2*)(out + (size_t)eB * UNITS);
        orB[lane] = make_float2(w0B, w1B);
    }
}

extern "C" void kernel_launch(void* const* d_in, const int* in_sizes, int n_in,
                              void* d_out, int out_size, void* d_ws, size_t ws_size,
                              hipStream_t stream) {
    const float* inputs = (const float*)d_in[0];
    const float* params = (const float*)d_in[1];
    float* out = (float*)d_out;

    const int B = in_sizes[0] / (UNITS + 1);        // 4096
    const int n_waves = (B + 1) / 2;                // 2 elements per wave
    const int waves_per_block = 4;                  // 256 threads
    const int grid = (n_waves + waves_per_block - 1) / waves_per_block;

    expv_kernel<<<grid, 64 * waves_per_block, 0, stream>>>(inputs, params, out, B);
}